// Round 11
// baseline (297.458 us; speedup 1.0000x reference)
//
#include <hip/hip_runtime.h>

// TeamMovementModel R11: R10 with the hop2 cross-lane direction FIXED.
// R10 failed (absmax 0.149) because DPP row_ror:12 is dst[i]=src[(i-12)%16]
// = src[(i+4)%16]: lane 4 pulled from lane 8, not lane 0 (row_shr:N is
// dst[i]=src[i-N], so ror:N = src[(i-N) mod 16]). Hop1's ror8 only worked in
// R7/R8 because +-8 rotation is symmetric. Fix: hop2 uses ds_swizzle xor4
// (offset 0x101F, involution -> direction-proof, encoding from the ISA doc's
// butterfly pattern). Structure unchanged vs R10:
//  - NB=4, 256-thr blocks (4 waves), 368 blocks -> 2 INDEPENDENT blocks/CU:
//    SIMD-cohabiting waves come from different blocks; stalls mutually hide
//    (R8 measured ~1270 cyc/step unhidden stall with lockstep waves).
//  - Wave owns M=128 gate rows: 8 m-tiles x 5 kt = 40 MFMA/step; afr = 160
//    regs pinned to AGPRs via loop-carried "+a" asm (split statements).
//  - zero4 C-operand: aug-tile MFMA writes acc directly (no per-step init).
// Lane mapping after both hops: lane (q,nn) holds gate g rows r0..r0+1 of
// col nn&3, where r0 = 32w + 16*bit2 + 4q + 2*bit3.

#define HDIM 128
#define TSTEPS 128
#define NPLAYER 1408
#define NSEQ 1472
#define NB 4
#define NBLK (NSEQ / NB)        // 368
#define NPBLK (NPLAYER / NB)    // 352
#define KT 5                    // k-tiles of 32 (K_aug = 160)
#define BSTR 168                // fp16 per B row (336 B stride)
#define XSTR 258                // floats per x col

typedef _Float16 f16x8 __attribute__((ext_vector_type(8)));
typedef _Float16 f16x2 __attribute__((ext_vector_type(2)));
typedef float    f32x4 __attribute__((ext_vector_type(4)));

#define LOG2E 1.44269504f

__device__ __forceinline__ float rcp_fast(float x) { return __builtin_amdgcn_rcpf(x); }
__device__ __forceinline__ float sigmoid_f(float x) {
    return rcp_fast(1.0f + __builtin_amdgcn_exp2f(-LOG2E * x));
}
__device__ __forceinline__ float tanh_f(float x) {
    return 1.0f - 2.0f * rcp_fast(__builtin_amdgcn_exp2f(2.0f * LOG2E * x) + 1.0f);
}
__device__ __forceinline__ float dpp_xor8(float x) {   // +-8 rotate in 16 = lane^8 (symmetric)
    return __int_as_float(__builtin_amdgcn_update_dpp(
        __float_as_int(x), __float_as_int(x), 0x128, 0xF, 0xF, false));
}
__device__ __forceinline__ float swz_xor4(float x) {   // lane^4, involution (ISA BitMode)
    return __int_as_float(__builtin_amdgcn_ds_swizzle(__float_as_int(x), 0x101F));
}

__global__ void __launch_bounds__(256)
__attribute__((amdgpu_waves_per_eu(2, 2)))
lstm_kernel(const float* __restrict__ x_players, const float* __restrict__ x_ball,
            const float* __restrict__ p_w_ih, const float* __restrict__ p_w_hh,
            const float* __restrict__ p_b_ih, const float* __restrict__ p_b_hh,
            const float* __restrict__ b_w_ih, const float* __restrict__ b_w_hh,
            const float* __restrict__ b_b_ih, const float* __restrict__ b_b_hh,
            float* __restrict__ h_all)
{
    const int tid  = threadIdx.x;
    const int blk  = blockIdx.x;          // 0..367; 352.. are ball blocks
    const int w    = tid >> 6;            // wave 0..3 -> h-rows [32w, 32w+32)
    const int lane = tid & 63;
    const int nn   = lane & 15;           // MFMA n / m index
    const int q    = lane >> 4;           // MFMA quad
    const int bit2 = (nn >> 2) & 1;       // -> row-half hh
    const int bit3 = (nn >> 3) & 1;       // -> reg-pair

    const bool ball = (blk >= NPBLK);
    const float* w_ih = ball ? b_w_ih : p_w_ih;
    const float* w_hh = ball ? b_w_hh : p_w_hh;
    const float* bih  = ball ? b_b_ih : p_b_ih;
    const float* bhh  = ball ? b_b_hh : p_b_hh;
    const float* xg   = ball ? (x_ball    + (size_t)(blk - NPBLK) * NB * TSTEPS * 2)
                             : (x_players + (size_t)blk * NB * TSTEPS * 2);

    __shared__ __align__(16) _Float16 b_sh[2][NB * BSTR];
    __shared__ __align__(16) float x_sh[NB * XSTR];

    for (int i = tid; i < NB * 256; i += 256)
        x_sh[(i >> 8) * XSTR + (i & 255)] = xg[i];
    for (int i = tid; i < 2 * NB * BSTR / 2; i += 256)
        ((int*)b_sh)[i] = 0;

    // ---- A fragments: tile mi = 2g+hh covers rows g*128 + 32w + 16hh + m.
    // a[j] = A[m=nn][k=32kt+8q+j]; kt=4 aug: k=128:wi0 129:wi1 130:bias
    f16x8 afr[8][KT];
    #pragma unroll
    for (int g = 0; g < 4; ++g)
        #pragma unroll
        for (int hh = 0; hh < 2; ++hh) {
            const int mi = 2 * g + hh;
            const int r  = g * HDIM + w * 32 + hh * 16 + nn;
            const float* wr = w_hh + (size_t)r * HDIM;
            #pragma unroll
            for (int kt = 0; kt < 4; ++kt) {
                const float* p = wr + kt * 32 + q * 8;
                f16x8 a8;
                #pragma unroll
                for (int j = 0; j < 8; ++j) a8[j] = (_Float16)p[j];
                afr[mi][kt] = a8;
            }
            f16x8 a8 = {};
            if (q == 0) {
                a8[0] = (_Float16)w_ih[2 * r];
                a8[1] = (_Float16)w_ih[2 * r + 1];
                a8[2] = (_Float16)(bih[r] + bhh[r]);
            }
            afr[mi][4] = a8;
        }

    const int colh = nn & 3;                                // owned seq col
    const int r0   = w * 32 + bit2 * 16 + q * 4 + bit3 * 2; // first owned h-row
    float c0 = 0.f, c1 = 0.f, h0 = 0.f, h1 = 0.f;

    // persistent zero C-operand for the aug-tile MFMA
    f32x4 zero4 = (f32x4){0.f, 0.f, 0.f, 0.f};
    asm volatile("" : "+v"(zero4));

    __syncthreads();
    if (tid < NB) {   // x(0) into buf0; '1' aug col into both buffers
        _Float16* br0 = &b_sh[0][tid * BSTR];
        br0[128] = (_Float16)x_sh[tid * XSTR];
        br0[129] = (_Float16)x_sh[tid * XSTR + 1];
        br0[130] = (_Float16)1.0f;
        b_sh[1][tid * BSTR + 130] = (_Float16)1.0f;
    }
    __syncthreads();

    f16x8 bfr[KT] = {};   // lanes nn>=4 keep constant-zero B frags

    auto substep = [&](int s, const _Float16* bc, _Float16* bn, bool last) {
        if (nn < NB) {
            #pragma unroll
            for (int kt = 0; kt < KT; ++kt)
                bfr[kt] = *(const f16x8*)(bc + nn * BSTR + kt * 32 + q * 8);
        }

        f32x4 acc[8];
        // aug tile first: acc = W_ih@x + bias (+0)
        #pragma unroll
        for (int mi = 0; mi < 8; ++mi)
            acc[mi] = __builtin_amdgcn_mfma_f32_16x16x32_f16(afr[mi][4], bfr[4], zero4, 0, 0, 0);
        #pragma unroll
        for (int kt = 0; kt < 4; ++kt)
            #pragma unroll
            for (int mi = 0; mi < 8; ++mi)
                acc[mi] = __builtin_amdgcn_mfma_f32_16x16x32_f16(afr[mi][kt], bfr[kt], acc[mi], 0, 0, 0);

        // x(s+1) into next buffer (independent of act chain)
        if (!last && tid < NB) {
            const float x0 = x_sh[tid * XSTR + 2 * (s + 1)];
            const float x1 = x_sh[tid * XSTR + 2 * (s + 1) + 1];
            *(f16x2*)&bn[tid * BSTR + 128] = (f16x2){(_Float16)x0, (_Float16)x1};
        }

        // hop1 (lane^8 via DPP, symmetric): u[mi][j] = tile-rows 4q+2*bit3+j, col nn&7
        float u[8][2];
        #pragma unroll
        for (int mi = 0; mi < 8; ++mi) {
            const float r2 = dpp_xor8(acc[mi][2]);
            const float r3 = dpp_xor8(acc[mi][3]);
            u[mi][0] = bit3 ? r2 : acc[mi][0];
            u[mi][1] = bit3 ? r3 : acc[mi][1];
        }
        // hop2 (lane^4 via ds_swizzle, involution): v[g][j] = gate g, rows r0+j, col nn&3
        float v[4][2];
        #pragma unroll
        for (int g = 0; g < 4; ++g) {
            const float p0 = swz_xor4(u[2 * g + 1][0]);
            const float p1 = swz_xor4(u[2 * g + 1][1]);
            v[g][0] = bit2 ? p0 : u[2 * g][0];
            v[g][1] = bit2 ? p1 : u[2 * g][1];
        }

        const float i0 = sigmoid_f(v[0][0]), i1 = sigmoid_f(v[0][1]);
        const float f0 = sigmoid_f(v[1][0]), f1 = sigmoid_f(v[1][1]);
        const float g0 = tanh_f(v[2][0]),    g1 = tanh_f(v[2][1]);
        const float o0 = sigmoid_f(v[3][0]), o1 = sigmoid_f(v[3][1]);
        c0 = __builtin_fmaf(f0, c0, i0 * g0);
        c1 = __builtin_fmaf(f1, c1, i1 * g1);
        h0 = o0 * tanh_f(c0);
        h1 = o1 * tanh_f(c1);

        if (!last) {
            *(f16x2*)&bn[colh * BSTR + r0] = (f16x2){(_Float16)h0, (_Float16)h1};
            __syncthreads();
        }
    };

    _Float16* b0 = &b_sh[0][0];
    _Float16* b1 = &b_sh[1][0];
    #pragma unroll 1
    for (int it = 0; it < TSTEPS / 2 - 1; ++it) {   // steps 0..125
        substep(2 * it,     b0, b1, false);
        substep(2 * it + 1, b1, b0, false);
        // loop-carried AGPR pins (split statements): block rematerialization
        asm volatile("" : "+a"(afr[0][0]), "+a"(afr[0][1]), "+a"(afr[0][2]), "+a"(afr[0][3]), "+a"(afr[0][4]));
        asm volatile("" : "+a"(afr[1][0]), "+a"(afr[1][1]), "+a"(afr[1][2]), "+a"(afr[1][3]), "+a"(afr[1][4]));
        asm volatile("" : "+a"(afr[2][0]), "+a"(afr[2][1]), "+a"(afr[2][2]), "+a"(afr[2][3]), "+a"(afr[2][4]));
        asm volatile("" : "+a"(afr[3][0]), "+a"(afr[3][1]), "+a"(afr[3][2]), "+a"(afr[3][3]), "+a"(afr[3][4]));
        asm volatile("" : "+a"(afr[4][0]), "+a"(afr[4][1]), "+a"(afr[4][2]), "+a"(afr[4][3]), "+a"(afr[4][4]));
        asm volatile("" : "+a"(afr[5][0]), "+a"(afr[5][1]), "+a"(afr[5][2]), "+a"(afr[5][3]), "+a"(afr[5][4]));
        asm volatile("" : "+a"(afr[6][0]), "+a"(afr[6][1]), "+a"(afr[6][2]), "+a"(afr[6][3]), "+a"(afr[6][4]));
        asm volatile("" : "+a"(afr[7][0]), "+a"(afr[7][1]), "+a"(afr[7][2]), "+a"(afr[7][3]), "+a"(afr[7][4]));
        asm volatile("" : "+v"(zero4));
    }
    substep(126, b0, b1, false);
    substep(127, b1, b0, true);    // peeled: no h-write, no barrier

    float* hp = h_all + (size_t)(blk * NB + colh) * HDIM + r0;
    hp[0] = h0; hp[1] = h1;
}

// FC: 176 blocks x 256 thr; block = 8 players. comb[p] = [player_h ; ball_h].
__global__ void __launch_bounds__(256)
fc_kernel(const float* __restrict__ h_all, const float* __restrict__ fc_w,
          const float* __restrict__ fc_b, float* __restrict__ out)
{
    const int blk = blockIdx.x;        // players [8*blk, 8*blk+8)
    const int tid = threadIdx.x;

    __shared__ __align__(16) float comb[8][2 * HDIM];
    for (int i = tid; i < 8 * HDIM; i += 256) {
        const int p = i >> 7, off = i & 127;
        const int gp = 8 * blk + p;
        comb[p][off]        = h_all[(size_t)gp * HDIM + off];
        comb[p][HDIM + off] = h_all[(size_t)(NPLAYER + gp / 22) * HDIM + off];
    }
    __syncthreads();

    for (int o = tid; o < 8 * 40; o += 256) {
        const int p = o / 40, row = o - p * 40;
        const float* wr = fc_w + (size_t)row * 2 * HDIM;
        const float* cp = &comb[p][0];
        float a0 = fc_b[row], a1 = 0.f, a2 = 0.f, a3 = 0.f;
        #pragma unroll
        for (int k = 0; k < 2 * HDIM; k += 4) {
            float4 wv = *(const float4*)(wr + k);
            float4 cv = *(const float4*)(cp + k);
            a0 = __builtin_fmaf(wv.x, cv.x, a0);
            a1 = __builtin_fmaf(wv.y, cv.y, a1);
            a2 = __builtin_fmaf(wv.z, cv.z, a2);
            a3 = __builtin_fmaf(wv.w, cv.w, a3);
        }
        out[(size_t)(8 * blk + p) * 40 + row] = (a0 + a1) + (a2 + a3);
    }
}

extern "C" void kernel_launch(void* const* d_in, const int* in_sizes, int n_in,
                              void* d_out, int out_size, void* d_ws, size_t ws_size,
                              hipStream_t stream) {
    const float* x_players = (const float*)d_in[0];
    const float* x_ball    = (const float*)d_in[1];
    const float* p_w_ih    = (const float*)d_in[2];
    const float* p_w_hh    = (const float*)d_in[3];
    const float* p_b_ih    = (const float*)d_in[4];
    const float* p_b_hh    = (const float*)d_in[5];
    const float* b_w_ih    = (const float*)d_in[6];
    const float* b_w_hh    = (const float*)d_in[7];
    const float* b_b_ih    = (const float*)d_in[8];
    const float* b_b_hh    = (const float*)d_in[9];
    const float* fc_w      = (const float*)d_in[10];
    const float* fc_b      = (const float*)d_in[11];

    float* h_all = (float*)d_ws;   // NSEQ * HDIM floats

    lstm_kernel<<<dim3(NBLK), dim3(256), 0, stream>>>(
        x_players, x_ball, p_w_ih, p_w_hh, p_b_ih, p_b_hh,
        b_w_ih, b_w_hh, b_b_ih, b_b_hh, h_all);

    fc_kernel<<<dim3(NPLAYER / 8), dim3(256), 0, stream>>>(
        h_all, fc_w, fc_b, (float*)d_out);
}

// Round 12
// 180.509 us; speedup vs baseline: 1.6479x; 1.6479x over previous
//
#include <hip/hip_runtime.h>

// TeamMovementModel R12: R8's proven LSTM core (108.8us, no spill) + FUSED FC.
// R11 post-mortem: the R9/R10/R11 8-tile structure needs 160 AGPR + ~128 VGPR
// = 288 regs > 256/wave budget at 2 waves/EU -> scratch spill (WRITE 25.7MB),
// 232us. Reverted. New target: the persistent ~70-90us total-minus-lstm gap
// (R3..R11). Fix: ONE kernel. FC is split as
//   out = fc_w[:, :128] @ player_h  +  fc_w[:, 128:] @ ball_h  +  fc_b
// Player blocks (0..175) atomicAdd their term; ball blocks (176..183) compute
// v_b = fc_w[:,128:] @ ball_h per batch and atomicAdd-broadcast to the batch's
// 22 players. Adds commute -> no inter-block ordering assumed (G16-safe).
// d_out is zeroed by hipMemsetAsync on the stream (graph-capture-safe).

#define HDIM 128
#define TSTEPS 128
#define NPLAYER 1408
#define NSEQ 1472
#define NB 8
#define NBLK (NSEQ / NB)        // 184
#define NPBLK (NPLAYER / NB)    // 176
#define KT 5                    // k-tiles of 32 (K_aug = 160)
#define BSTR 168                // fp16 per B row (336 B stride)
#define XSTR 258                // floats per x col
#define HSTR 132                // floats per hbuf row (16B-aligned, pad 4)

typedef _Float16 f16x8 __attribute__((ext_vector_type(8)));
typedef _Float16 f16x2 __attribute__((ext_vector_type(2)));
typedef float    f32x4 __attribute__((ext_vector_type(4)));

#define LOG2E 1.44269504f

__device__ __forceinline__ float rcp_fast(float x) { return __builtin_amdgcn_rcpf(x); }
__device__ __forceinline__ float sigmoid_f(float x) {
    return rcp_fast(1.0f + __builtin_amdgcn_exp2f(-LOG2E * x));
}
__device__ __forceinline__ float tanh_f(float x) {
    return 1.0f - 2.0f * rcp_fast(__builtin_amdgcn_exp2f(2.0f * LOG2E * x) + 1.0f);
}
__device__ __forceinline__ float dpp_xor8(float x) {   // +-8 rotate in 16 = lane^8 (symmetric)
    return __int_as_float(__builtin_amdgcn_update_dpp(
        __float_as_int(x), __float_as_int(x), 0x128, 0xF, 0xF, false));
}

__global__ void __launch_bounds__(512)
__attribute__((amdgpu_waves_per_eu(2, 2)))
lstm_fc_kernel(const float* __restrict__ x_players, const float* __restrict__ x_ball,
               const float* __restrict__ p_w_ih, const float* __restrict__ p_w_hh,
               const float* __restrict__ p_b_ih, const float* __restrict__ p_b_hh,
               const float* __restrict__ b_w_ih, const float* __restrict__ b_w_hh,
               const float* __restrict__ b_b_ih, const float* __restrict__ b_b_hh,
               const float* __restrict__ fc_w, const float* __restrict__ fc_b,
               float* __restrict__ out)
{
    const int tid  = threadIdx.x;
    const int blk  = blockIdx.x;          // 0..183; 176..183 ball
    const int w    = tid >> 6;            // wave -> h-rows [16w, 16w+16)
    const int lane = tid & 63;
    const int nn   = lane & 15;           // MFMA n (col)
    const int q    = lane >> 4;           // MFMA quad

    const bool ball = (blk >= NPBLK);
    const float* w_ih = ball ? b_w_ih : p_w_ih;
    const float* w_hh = ball ? b_w_hh : p_w_hh;
    const float* bih  = ball ? b_b_ih : p_b_ih;
    const float* bhh  = ball ? b_b_hh : p_b_hh;
    const float* xg   = ball ? (x_ball    + (size_t)(blk - NPBLK) * NB * TSTEPS * 2)
                             : (x_players + (size_t)blk * NB * TSTEPS * 2);

    __shared__ __align__(16) _Float16 b_sh[2][NB * BSTR];
    __shared__ __align__(16) float x_sh[NB * XSTR];
    __shared__ __align__(16) float hbuf[NB * HSTR];   // final h, fp32
    __shared__ float vout[NB * 40];                   // ball-path per-batch fc part

    for (int i = tid; i < NB * 256; i += 512)
        x_sh[(i >> 8) * XSTR + (i & 255)] = xg[i];
    for (int i = tid; i < 2 * NB * BSTR / 2; i += 512)
        ((int*)b_sh)[i] = 0;

    // ---- A fragments: gate mi, row r = mi*128 + 16w + nn.
    // a[j] = A[m=lane&15][k = 32kt + 8q + j]; kt=4 aug: k=128:wi0 129:wi1 130:bias
    f16x8 afr[4][KT];
    #pragma unroll
    for (int mi = 0; mi < 4; ++mi) {
        const int r = mi * HDIM + w * 16 + nn;
        const float* wr = w_hh + (size_t)r * HDIM;
        #pragma unroll
        for (int kt = 0; kt < 4; ++kt) {
            const float* p = wr + kt * 32 + q * 8;
            f16x8 a8;
            #pragma unroll
            for (int j = 0; j < 8; ++j) a8[j] = (_Float16)p[j];
            afr[mi][kt] = a8;
        }
        f16x8 a8 = {};
        if (q == 0) {
            a8[0] = (_Float16)w_ih[2 * r];
            a8[1] = (_Float16)w_ih[2 * r + 1];
            a8[2] = (_Float16)(bih[r] + bhh[r]);
        }
        afr[mi][4] = a8;
    }

    const int colh   = nn & 7;                  // owned seq col
    const int rowoff = (nn < 8) ? 0 : 2;        // reg-split via DPP
    const int hrow   = w * 16 + 4 * q + rowoff; // first of 2 owned h-rows
    float c0 = 0.f, c1 = 0.f;
    float h0 = 0.f, h1 = 0.f;

    __syncthreads();
    if (tid < NB) {   // x(0) into buf0; '1' aug col into both buffers
        _Float16* br0 = &b_sh[0][tid * BSTR];
        br0[128] = (_Float16)x_sh[tid * XSTR];
        br0[129] = (_Float16)x_sh[tid * XSTR + 1];
        br0[130] = (_Float16)1.0f;
        b_sh[1][tid * BSTR + 130] = (_Float16)1.0f;
    }
    __syncthreads();

    f16x8 bfr[KT] = {};   // lanes nn>=8 keep constant-zero B frags

    auto substep = [&](int s, const _Float16* bc, _Float16* bn, bool last) {
        if (nn < 8) {
            #pragma unroll
            for (int kt = 0; kt < KT; ++kt)
                bfr[kt] = *(const f16x8*)(bc + nn * BSTR + kt * 32 + q * 8);
        }

        f32x4 acc[4];
        #pragma unroll
        for (int mi = 0; mi < 4; ++mi) acc[mi] = (f32x4){0.f, 0.f, 0.f, 0.f};
        #pragma unroll
        for (int kt = 0; kt < KT; ++kt)
            #pragma unroll
            for (int mi = 0; mi < 4; ++mi)
                acc[mi] = __builtin_amdgcn_mfma_f32_16x16x32_f16(afr[mi][kt], bfr[kt], acc[mi], 0, 0, 0);

        if (!last && tid < NB) {
            const float x0 = x_sh[tid * XSTR + 2 * (s + 1)];
            const float x1 = x_sh[tid * XSTR + 2 * (s + 1) + 1];
            *(f16x2*)&bn[tid * BSTR + 128] = (f16x2){(_Float16)x0, (_Float16)x1};
        }

        // reg-split swap: lane nn<8 keeps regs {0,1} of col nn,
        // lane nn>=8 takes partner's regs {2,3} of col nn-8
        float u0[4], u1[4];
        #pragma unroll
        for (int mi = 0; mi < 4; ++mi) {
            const float r2 = dpp_xor8(acc[mi][2]);
            const float r3 = dpp_xor8(acc[mi][3]);
            u0[mi] = (nn < 8) ? acc[mi][0] : r2;
            u1[mi] = (nn < 8) ? acc[mi][1] : r3;
        }
        const float i0 = sigmoid_f(u0[0]), i1 = sigmoid_f(u1[0]);
        const float f0 = sigmoid_f(u0[1]), f1 = sigmoid_f(u1[1]);
        const float g0 = tanh_f(u0[2]),    g1 = tanh_f(u1[2]);
        const float o0 = sigmoid_f(u0[3]), o1 = sigmoid_f(u1[3]);
        c0 = __builtin_fmaf(f0, c0, i0 * g0);
        c1 = __builtin_fmaf(f1, c1, i1 * g1);
        h0 = o0 * tanh_f(c0);
        h1 = o1 * tanh_f(c1);

        if (!last) {
            *(f16x2*)&bn[colh * BSTR + hrow] = (f16x2){(_Float16)h0, (_Float16)h1};
            __syncthreads();
        }
    };

    _Float16* b0 = &b_sh[0][0];
    _Float16* b1 = &b_sh[1][0];
    #pragma unroll 1
    for (int it = 0; it < TSTEPS / 2 - 1; ++it) {   // steps 0..125
        substep(2 * it,     b0, b1, false);
        substep(2 * it + 1, b1, b0, false);
        // loop-carried AGPR pins: block rematerialization (R1..R5 failure mode)
        asm volatile("" : "+a"(afr[0][0]), "+a"(afr[0][1]), "+a"(afr[0][2]), "+a"(afr[0][3]), "+a"(afr[0][4]));
        asm volatile("" : "+a"(afr[1][0]), "+a"(afr[1][1]), "+a"(afr[1][2]), "+a"(afr[1][3]), "+a"(afr[1][4]));
        asm volatile("" : "+a"(afr[2][0]), "+a"(afr[2][1]), "+a"(afr[2][2]), "+a"(afr[2][3]), "+a"(afr[2][4]));
        asm volatile("" : "+a"(afr[3][0]), "+a"(afr[3][1]), "+a"(afr[3][2]), "+a"(afr[3][3]), "+a"(afr[3][4]));
    }
    substep(126, b0, b1, false);
    substep(127, b1, b0, true);    // peeled: no h-write, no barrier

    // ---- final h -> LDS (fp32), then fused FC epilogue ----
    hbuf[colh * HSTR + hrow]     = h0;
    hbuf[colh * HSTR + hrow + 1] = h1;
    __syncthreads();

    if (!ball) {
        // player part: out[gp*40+row] += fc_b[row] + fc_w[row, 0:128] . h(gp)
        for (int o = tid; o < NB * 40; o += 512) {
            const int j = o / 40, row = o - j * 40;
            const float* wr = fc_w + (size_t)row * 2 * HDIM;        // cols 0..127
            const float* hp = &hbuf[j * HSTR];
            float a0 = fc_b[row], a1 = 0.f, a2 = 0.f, a3 = 0.f;
            #pragma unroll
            for (int k = 0; k < HDIM; k += 4) {
                float4 wv = *(const float4*)(wr + k);
                float4 hv = *(const float4*)(hp + k);
                a0 = __builtin_fmaf(wv.x, hv.x, a0);
                a1 = __builtin_fmaf(wv.y, hv.y, a1);
                a2 = __builtin_fmaf(wv.z, hv.z, a2);
                a3 = __builtin_fmaf(wv.w, hv.w, a3);
            }
            atomicAdd(&out[(size_t)(NB * blk + j) * 40 + row], (a0 + a1) + (a2 + a3));
        }
    } else {
        // ball part: v[c][row] = fc_w[row, 128:256] . ball_h(batch), then
        // broadcast-add to the batch's 22 players.
        for (int o = tid; o < NB * 40; o += 512) {
            const int c = o / 40, row = o - c * 40;
            const float* wr = fc_w + (size_t)row * 2 * HDIM + HDIM;  // cols 128..255
            const float* hp = &hbuf[c * HSTR];
            float a0 = 0.f, a1 = 0.f, a2 = 0.f, a3 = 0.f;
            #pragma unroll
            for (int k = 0; k < HDIM; k += 4) {
                float4 wv = *(const float4*)(wr + k);
                float4 hv = *(const float4*)(hp + k);
                a0 = __builtin_fmaf(wv.x, hv.x, a0);
                a1 = __builtin_fmaf(wv.y, hv.y, a1);
                a2 = __builtin_fmaf(wv.z, hv.z, a2);
                a3 = __builtin_fmaf(wv.w, hv.w, a3);
            }
            vout[c * 40 + row] = (a0 + a1) + (a2 + a3);
        }
        __syncthreads();
        const int base_batch = (blk - NPBLK) * NB;
        for (int o = tid; o < NB * 22 * 40; o += 512) {
            const int c = o / 880, rem = o - c * 880;
            const int p = rem / 40, row = rem - p * 40;
            atomicAdd(&out[(size_t)((base_batch + c) * 22 + p) * 40 + row],
                      vout[c * 40 + row]);
        }
    }
}

extern "C" void kernel_launch(void* const* d_in, const int* in_sizes, int n_in,
                              void* d_out, int out_size, void* d_ws, size_t ws_size,
                              hipStream_t stream) {
    const float* x_players = (const float*)d_in[0];
    const float* x_ball    = (const float*)d_in[1];
    const float* p_w_ih    = (const float*)d_in[2];
    const float* p_w_hh    = (const float*)d_in[3];
    const float* p_b_ih    = (const float*)d_in[4];
    const float* p_b_hh    = (const float*)d_in[5];
    const float* b_w_ih    = (const float*)d_in[6];
    const float* b_w_hh    = (const float*)d_in[7];
    const float* b_b_ih    = (const float*)d_in[8];
    const float* b_b_hh    = (const float*)d_in[9];
    const float* fc_w      = (const float*)d_in[10];
    const float* fc_b      = (const float*)d_in[11];

    // zero the output: both block types accumulate into it atomically
    hipMemsetAsync(d_out, 0, (size_t)out_size * sizeof(float), stream);

    lstm_fc_kernel<<<dim3(NBLK), dim3(512), 0, stream>>>(
        x_players, x_ball, p_w_ih, p_w_hh, p_b_ih, p_b_hh,
        b_w_ih, b_w_hh, b_b_ih, b_b_hh, fc_w, fc_b, (float*)d_out);
}